// Round 1
// baseline (332.108 us; speedup 1.0000x reference)
//
#include <hip/hip_runtime.h>

#define DIMV 1024
#define SSZ 512
#define MSZ 4096
#define LSZ 8192
#define KPROM 128
#define NCAND 16384

typedef __attribute__((ext_vector_type(4))) float f32x4;
typedef __attribute__((ext_vector_type(4))) unsigned int u32x4;
typedef __attribute__((ext_vector_type(4))) unsigned short u16x4;
typedef __attribute__((ext_vector_type(8))) __bf16 bf16x8;

// ---------------- output layout (float element offsets) ----------------
#define OUT_S 0ull
#define OUT_M 524288ull
#define OUT_L 4718592ull
#define OUT_MU 13107200ull
#define OUT_LU 13111296ull
#define OUT_SPTR 13119488ull

// ---- scratch lives inside the out_l region (written last), float units ----
#define SC_BF16 0ull          // 4096x1024 bf16 (2,097,152 float slots)
#define SC_NORMS 2100000ull   // 16384
#define SC_TOPIDX 2117000ull  // 128 ints
#define SC_LPART 2120000ull   // 128*1024
#define SC_LMEAN 2260000ull   // 1024
#define SC_Q 2262000ull       // 1024
#define SC_RPART 2270000ull   // 128*1024
#define SC_R 2410000ull       // 1024
#define SC_CSCAL 2412000ull   // 1
#define SC_LOGITS 2413000ull  // 512
#define SC_BEST 2414000ull    // [0] int best_s_idx, [1] float cnorm
#define SC_MNORM 2415000ull   // 4096
#define SC_SIMS 2420000ull    // 4096
#define SC_PPV 2425000ull     // 528 partial max vals
#define SC_PPI 2426000ull     // 528 partial max flat idx
#define SC_DEC 2427000ull     // ints[0..3]=branch,i1,i2,pad; floats[4..5]=u1,u2

__device__ __forceinline__ float wave_sum(float v) {
#pragma unroll
  for (int o = 32; o > 0; o >>= 1) v += __shfl_down(v, o, 64);
  return v;
}
__device__ __forceinline__ int wave_sum_i(int v) {
#pragma unroll
  for (int o = 32; o > 0; o >>= 1) v += __shfl_down(v, o, 64);
  return v;
}
__device__ __forceinline__ void wave_maxidx(float& v, int& i) {
#pragma unroll
  for (int o = 32; o > 0; o >>= 1) {
    float ov = __shfl_down(v, o, 64);
    int oi = __shfl_down(i, o, 64);
    if (ov > v || (ov == v && oi < i)) { v = ov; i = oi; }
  }
}
__device__ __forceinline__ void wave_minidx(float& v, int& i) {
#pragma unroll
  for (int o = 32; o > 0; o >>= 1) {
    float ov = __shfl_down(v, o, 64);
    int oi = __shfl_down(i, o, 64);
    if (ov < v || (ov == v && oi < i)) { v = ov; i = oi; }
  }
}
__device__ __forceinline__ unsigned short f2bf(float x) {  // RNE float->bf16
  unsigned u = __float_as_uint(x);
  return (unsigned short)((u + 0x7FFFu + ((u >> 16) & 1u)) >> 16);
}

// ---------------- K1: candidate row norms (16384 rows) ----------------
__global__ void k_cand_norms(const float* __restrict__ cand, float* __restrict__ norms) {
  int lane = threadIdx.x & 63, w = threadIdx.x >> 6;
  int row = blockIdx.x * 4 + w;
  const f32x4* p = (const f32x4*)(cand + (size_t)row * DIMV);
  float s = 0.f;
#pragma unroll
  for (int c = 0; c < 4; ++c) {
    f32x4 v = p[c * 64 + lane];
    s += v.x * v.x + v.y * v.y + v.z * v.z + v.w * v.w;
  }
  s = wave_sum(s);
  if (lane == 0) norms[row] = sqrtf(s);
}

// ---------------- K2: exact stable top-128 (radix select + rank sort) ----------------
__device__ int scan_excl_1024(int v, int* sh, int* total) {
  int t = threadIdx.x;
  sh[t] = v;
  __syncthreads();
  for (int o = 1; o < 1024; o <<= 1) {
    int x = (t >= o) ? sh[t - o] : 0;
    __syncthreads();
    sh[t] += x;
    __syncthreads();
  }
  int incl = sh[t];
  *total = sh[1023];
  __syncthreads();
  return incl - v;
}

__global__ void k_topk(const float* __restrict__ norms, int* __restrict__ topidx) {
  __shared__ int sh[1024];
  __shared__ int s_w[16];
  __shared__ int s_tot;
  __shared__ unsigned s_selkey[KPROM];
  __shared__ int s_selidx[KPROM];
  int t = threadIdx.x, lane = t & 63, w = t >> 6;
  unsigned key[16];
#pragma unroll
  for (int j = 0; j < 16; ++j) key[j] = __float_as_uint(norms[t * 16 + j]);  // norms > 0: bit order == value order

  unsigned prefix = 0;
  int remaining = KPROM;
  for (int bit = 31; bit >= 0; --bit) {
    unsigned himask = (bit == 31) ? 0u : (0xFFFFFFFFu << (bit + 1));
    int c = 0;
#pragma unroll
    for (int j = 0; j < 16; ++j)
      c += (((key[j] & himask) == prefix) && ((key[j] >> bit) & 1u)) ? 1 : 0;
    c = wave_sum_i(c);
    if (lane == 0) s_w[w] = c;
    __syncthreads();
    if (t == 0) {
      int tot = 0;
      for (int i = 0; i < 16; ++i) tot += s_w[i];
      s_tot = tot;
    }
    __syncthreads();
    int tot = s_tot;
    __syncthreads();
    if (tot >= remaining) prefix |= (1u << bit);
    else remaining -= tot;
  }
  unsigned T = prefix;  // the 128th-largest key

  int cgt = 0, ceq = 0;
#pragma unroll
  for (int j = 0; j < 16; ++j) { cgt += (key[j] > T); ceq += (key[j] == T); }
  int total_gt, total_eq;
  int sgt = scan_excl_1024(cgt, sh, &total_gt);
  int seq = scan_excl_1024(ceq, sh, &total_eq);
  int need_eq = KPROM - total_gt;
  int g = sgt, e = seq;
#pragma unroll
  for (int j = 0; j < 16; ++j) {
    if (key[j] > T) { s_selkey[g] = key[j]; s_selidx[g] = t * 16 + j; ++g; }
    else if (key[j] == T) {
      if (e < need_eq) { s_selkey[total_gt + e] = key[j]; s_selidx[total_gt + e] = t * 16 + j; }
      ++e;
    }
  }
  __syncthreads();
  if (t < KPROM) {  // O(128^2) stable rank: value desc, index asc — matches lax.top_k
    unsigned mk = s_selkey[t];
    int mi = s_selidx[t];
    int rank = 0;
    for (int q2 = 0; q2 < KPROM; ++q2) {
      unsigned qk = s_selkey[q2];
      int qi = s_selidx[q2];
      rank += (qk > mk || (qk == mk && qi < mi)) ? 1 : 0;
    }
    topidx[rank] = mi;
  }
}

// ---------------- K3: build s_mem output + s_ptr_new ----------------
__global__ void k_write_s(const float* __restrict__ cand, const float* __restrict__ s_memory,
                          const int* __restrict__ topidx, const int* __restrict__ s_ptr,
                          float* __restrict__ out_s, float* __restrict__ out_sptr) {
  int r = blockIdx.x;
  int sp = s_ptr[0];
  int k = (r - sp + SSZ) & (SSZ - 1);
  const float* src = (k < KPROM) ? (cand + (size_t)topidx[k] * DIMV) : (s_memory + (size_t)r * DIMV);
  ((f32x4*)(out_s + (size_t)r * DIMV))[threadIdx.x] = ((const f32x4*)src)[threadIdx.x];
  if (r == 0 && threadIdx.x == 0) out_sptr[0] = (float)((sp + KPROM) % SSZ);
}

// ---------------- K4: l_memory column mean (2-stage) ----------------
__global__ void k_lpart(const float* __restrict__ l_memory, float* __restrict__ lpart) {
  int b = blockIdx.x, t = threadIdx.x;
  f32x4 a = {0.f, 0.f, 0.f, 0.f};
  const f32x4* base = (const f32x4*)(l_memory + (size_t)b * 64 * DIMV);
  for (int r = 0; r < 64; ++r) a += base[r * 256 + t];
  ((f32x4*)(lpart + (size_t)b * DIMV))[t] = a;
}
__global__ void k_lmean(const float* __restrict__ lpart, float* __restrict__ lmean) {
  int c = threadIdx.x;
  f32x4 a = {0.f, 0.f, 0.f, 0.f};
  for (int p = 0; p < 128; ++p) a += ((const f32x4*)lpart)[p * 256 + c];
  ((f32x4*)lmean)[c] = a * (1.f / 8192.f);
}

// ---------------- K5: q = wq @ lmean + bq ----------------
__global__ void k_q(const float* __restrict__ wq, const float* __restrict__ bq,
                    const float* __restrict__ lmean, float* __restrict__ qv) {
  int lane = threadIdx.x & 63, w = threadIdx.x >> 6;
  int d = blockIdx.x * 4 + w;
  const f32x4* row = (const f32x4*)(wq + (size_t)d * DIMV);
  const f32x4* lm = (const f32x4*)lmean;
  float s = 0.f;
#pragma unroll
  for (int c = 0; c < 4; ++c) {
    f32x4 a = row[c * 64 + lane], b = lm[c * 64 + lane];
    s += a.x * b.x + a.y * b.y + a.z * b.z + a.w * b.w;
  }
  s = wave_sum(s);
  if (lane == 0) qv[d] = s + bq[d];
}

// ---------------- K6: r = q @ wk (column sums), c = bk.q ----------------
__global__ void k_rpart(const float* __restrict__ wk, const float* __restrict__ qv, float* __restrict__ rpart) {
  int b = blockIdx.x, t = threadIdx.x;
  f32x4 a = {0.f, 0.f, 0.f, 0.f};
  for (int r = 0; r < 8; ++r) {
    float qd = qv[b * 8 + r];
    f32x4 v = ((const f32x4*)(wk + (size_t)(b * 8 + r) * DIMV))[t];
    a += v * qd;
  }
  ((f32x4*)(rpart + (size_t)b * DIMV))[t] = a;
}
__global__ void k_rfinal(const float* __restrict__ rpart, float* __restrict__ rv) {
  int c = threadIdx.x;
  f32x4 a = {0.f, 0.f, 0.f, 0.f};
  for (int p = 0; p < 128; ++p) a += ((const f32x4*)rpart)[p * 256 + c];
  ((f32x4*)rv)[c] = a;
}
__global__ void k_cscal(const float* __restrict__ bk, const float* __restrict__ qv, float* __restrict__ cs) {
  __shared__ float sw[4];
  int lane = threadIdx.x & 63, w = threadIdx.x >> 6;
  f32x4 a = ((const f32x4*)bk)[threadIdx.x];
  f32x4 b = ((const f32x4*)qv)[threadIdx.x];
  float s = a.x * b.x + a.y * b.y + a.z * b.z + a.w * b.w;
  s = wave_sum(s);
  if (lane == 0) sw[w] = s;
  __syncthreads();
  if (threadIdx.x == 0) cs[0] = sw[0] + sw[1] + sw[2] + sw[3];
}

// ---------------- K7: logits[s] = s_mem[s].r + c ----------------
__global__ void k_logits(const float* __restrict__ out_s, const float* __restrict__ rv,
                         const float* __restrict__ cs, float* __restrict__ logits) {
  int lane = threadIdx.x & 63, w = threadIdx.x >> 6;
  int srow = blockIdx.x * 4 + w;
  const f32x4* a = (const f32x4*)(out_s + (size_t)srow * DIMV);
  const f32x4* b = (const f32x4*)rv;
  float s = 0.f;
#pragma unroll
  for (int c = 0; c < 4; ++c) {
    f32x4 x = a[c * 64 + lane], y = b[c * 64 + lane];
    s += x.x * y.x + x.y * y.y + x.z * y.z + x.w * y.w;
  }
  s = wave_sum(s);
  if (lane == 0) logits[srow] = s + cs[0];
}

// ---------------- K8: best_s_idx = argmax(logits); cnorm = ||candidate|| ----------------
__global__ void k_argmax_logits(const float* __restrict__ logits, const float* __restrict__ out_s,
                                int* __restrict__ best, float* __restrict__ cnorm) {
  __shared__ float swv[4];
  __shared__ int swi[4];
  int t = threadIdx.x, lane = t & 63, w = t >> 6;
  float v0 = logits[t], v1 = logits[t + 256];
  float bv;
  int bidx;
  if (v1 > v0) { bv = v1; bidx = t + 256; } else { bv = v0; bidx = t; }
  wave_maxidx(bv, bidx);
  if (lane == 0) { swv[w] = bv; swi[w] = bidx; }
  __syncthreads();
  if (t == 0) {
    float a = swv[0]; int ai = swi[0];
    for (int i = 1; i < 4; ++i)
      if (swv[i] > a || (swv[i] == a && swi[i] < ai)) { a = swv[i]; ai = swi[i]; }
    best[0] = ai;
  }
  __syncthreads();
  int bi = best[0];
  f32x4 c4 = ((const f32x4*)(out_s + (size_t)bi * DIMV))[t];
  float s = c4.x * c4.x + c4.y * c4.y + c4.z * c4.z + c4.w * c4.w;
  s = wave_sum(s);
  __syncthreads();
  if (lane == 0) swv[w] = s;
  __syncthreads();
  if (t == 0) cnorm[0] = sqrtf(swv[0] + swv[1] + swv[2] + swv[3]);
}

// ---------------- K9: m row norms + sims vs candidate + bf16 copy of M ----------------
__global__ void k_msims(const float* __restrict__ m, const float* __restrict__ out_s,
                        const int* __restrict__ best, const float* __restrict__ cnorm,
                        unsigned short* __restrict__ mb, float* __restrict__ mnorm,
                        float* __restrict__ sims) {
  int lane = threadIdx.x & 63, w = threadIdx.x >> 6;
  int row = blockIdx.x * 4 + w;
  const f32x4* mp = (const f32x4*)(m + (size_t)row * DIMV);
  const f32x4* cp = (const f32x4*)(out_s + (size_t)best[0] * DIMV);
  float ss = 0.f, sd = 0.f;
#pragma unroll
  for (int c = 0; c < 4; ++c) {
    int i = c * 64 + lane;
    f32x4 v = mp[i], u = cp[i];
    ss += v.x * v.x + v.y * v.y + v.z * v.z + v.w * v.w;
    sd += v.x * u.x + v.y * u.y + v.z * u.z + v.w * u.w;
    u16x4 h;
    h.x = f2bf(v.x); h.y = f2bf(v.y); h.z = f2bf(v.z); h.w = f2bf(v.w);
    ((u16x4*)(mb + (size_t)row * DIMV))[i] = h;
  }
  ss = wave_sum(ss);
  sd = wave_sum(sd);
  if (lane == 0) {
    float n = sqrtf(ss);
    mnorm[row] = n;
    sims[row] = sd / (fmaxf(n, 1e-12f) * fmaxf(cnorm[0], 1e-12f));
  }
}

// ---------------- K10: lower-triangle pairwise cosine max (bf16 MFMA) ----------------
// block tile 128x128, 4 waves 2x2, wave tile 64x64 (16 x mfma_f32_16x16x32_bf16), BK=64
__global__ __launch_bounds__(256) void k_pairmax(const unsigned short* __restrict__ mb,
                                                 const float* __restrict__ mnorm,
                                                 float* __restrict__ pv, int* __restrict__ pidx) {
  __shared__ unsigned short At[128 * 72];  // pad 64->72 bf16: 2-way-max bank aliasing, 16B aligned rows
  __shared__ unsigned short Bt[128 * 72];
  __shared__ float spv[4];
  __shared__ int spi[4];
  int b = blockIdx.x;
  int bi = 0, acc0 = 0;
  while (acc0 + bi + 1 <= b) { acc0 += bi + 1; ++bi; }  // b -> (bi,bj), bi>=bj
  int bj = b - acc0;
  int t = threadIdx.x, lane = t & 63, w = t >> 6;
  int wr = w >> 1, wc = w & 1;
  int rl = lane & 15, kq = (lane >> 4) * 8, riq = (lane >> 4) * 4;
  int rowA0 = bi * 128, rowB0 = bj * 128;

  f32x4 acc[4][4];
  f32x4 z = {0.f, 0.f, 0.f, 0.f};
#pragma unroll
  for (int i = 0; i < 4; ++i)
#pragma unroll
    for (int j = 0; j < 4; ++j) acc[i][j] = z;

  for (int kc = 0; kc < DIMV; kc += 64) {
    __syncthreads();
#pragma unroll
    for (int c = 0; c < 4; ++c) {
      int chunk = c * 256 + t;  // 1024 x 16B chunks per tile
      int r = chunk >> 3, co = (chunk & 7) * 8;
      u32x4 va = *(const u32x4*)(mb + (size_t)(rowA0 + r) * DIMV + kc + co);
      u32x4 vb = *(const u32x4*)(mb + (size_t)(rowB0 + r) * DIMV + kc + co);
      *(u32x4*)(At + r * 72 + co) = va;
      *(u32x4*)(Bt + r * 72 + co) = vb;
    }
    __syncthreads();
#pragma unroll
    for (int ks = 0; ks < 64; ks += 32) {
      bf16x8 af[4], bfv[4];
#pragma unroll
      for (int ti = 0; ti < 4; ++ti)
        af[ti] = *(const bf16x8*)(At + (wr * 64 + ti * 16 + rl) * 72 + ks + kq);
#pragma unroll
      for (int tj = 0; tj < 4; ++tj)
        bfv[tj] = *(const bf16x8*)(Bt + (wc * 64 + tj * 16 + rl) * 72 + ks + kq);
#pragma unroll
      for (int ti = 0; ti < 4; ++ti)
#pragma unroll
        for (int tj = 0; tj < 4; ++tj)
          acc[ti][tj] = __builtin_amdgcn_mfma_f32_16x16x32_bf16(af[ti], bfv[tj], acc[ti][tj], 0, 0, 0);
    }
  }
  // epilogue: sim = dot/(ni*nj), strict lower triangle, track (max, min flat idx)
  float ni[16], nj[4];
#pragma unroll
  for (int ti = 0; ti < 4; ++ti)
#pragma unroll
    for (int r = 0; r < 4; ++r)
      ni[ti * 4 + r] = fmaxf(mnorm[rowA0 + wr * 64 + ti * 16 + riq + r], 1e-12f);
#pragma unroll
  for (int tj = 0; tj < 4; ++tj)
    nj[tj] = fmaxf(mnorm[rowB0 + wc * 64 + tj * 16 + rl], 1e-12f);

  float bv = -3.402823466e38f;
  int bidx = 0x7FFFFFFF;
#pragma unroll
  for (int ti = 0; ti < 4; ++ti)
#pragma unroll
    for (int tj = 0; tj < 4; ++tj)
#pragma unroll
      for (int r = 0; r < 4; ++r) {
        int gi = rowA0 + wr * 64 + ti * 16 + riq + r;   // C/D: row=(lane>>4)*4+reg
        int gj = rowB0 + wc * 64 + tj * 16 + rl;        // C/D: col=lane&15
        if (gi > gj) {
          float s = acc[ti][tj][r] / (ni[ti * 4 + r] * nj[tj]);
          int fi = gi * MSZ + gj;
          if (s > bv || (s == bv && fi < bidx)) { bv = s; bidx = fi; }
        }
      }
  wave_maxidx(bv, bidx);
  if (lane == 0) { spv[w] = bv; spi[w] = bidx; }
  __syncthreads();
  if (t == 0) {
    float a = spv[0]; int ai = spi[0];
    for (int i = 1; i < 4; ++i)
      if (spv[i] > a || (spv[i] == a && spi[i] < ai)) { a = spv[i]; ai = spi[i]; }
    pv[b] = a;
    pidx[b] = ai;
  }
}

// ---------------- K11: all scalar decisions ----------------
__global__ void k_decide(const float* __restrict__ pv, const int* __restrict__ pidx,
                         const float* __restrict__ sims, const float* __restrict__ mu,
                         const float* __restrict__ mnorm, const float* __restrict__ cnorm,
                         int nblk, int* __restrict__ dec_i, float* __restrict__ dec_f) {
  __shared__ float swv[4];
  __shared__ int swi[4];
  __shared__ float ssum[4];
  __shared__ int szf[4];
  __shared__ float s_res[2];
  __shared__ int s_resi[2];
  int t = threadIdx.x, lane = t & 63, w = t >> 6;

  // A: internal pairwise max
  float bv = -3.402823466e38f;
  int bidx = 0x7FFFFFFF;
  for (int i = t; i < nblk; i += 256) {
    float v = pv[i];
    int fi = pidx[i];
    if (v > bv || (v == bv && fi < bidx)) { bv = v; bidx = fi; }
  }
  wave_maxidx(bv, bidx);
  if (lane == 0) { swv[w] = bv; swi[w] = bidx; }
  __syncthreads();
  if (t == 0) {
    float a = swv[0]; int ai = swi[0];
    for (int i = 1; i < 4; ++i)
      if (swv[i] > a || (swv[i] == a && swi[i] < ai)) { a = swv[i]; ai = swi[i]; }
    s_res[0] = a; s_resi[0] = ai;
  }
  __syncthreads();

  // B: argmax(sims) first-occurrence
  bv = -3.402823466e38f;
  bidx = 0x7FFFFFFF;
#pragma unroll
  for (int j = 0; j < 16; ++j) {
    int i = t * 16 + j;
    float v = sims[i];
    if (v > bv) { bv = v; bidx = i; }
  }
  wave_maxidx(bv, bidx);
  if (lane == 0) { swv[w] = bv; swi[w] = bidx; }
  __syncthreads();
  if (t == 0) {
    float a = swv[0]; int ai = swi[0];
    for (int i = 1; i < 4; ++i)
      if (swv[i] > a || (swv[i] == a && swi[i] < ai)) { a = swv[i]; ai = swi[i]; }
    s_res[1] = a; s_resi[1] = ai;
  }
  __syncthreads();

  // C: mu stats (sum, argmin first-occurrence, any-zero)
  float sum = 0.f, mnv = 3.402823466e38f;
  int mni = 0x7FFFFFFF, zf = 0;
#pragma unroll
  for (int j = 0; j < 16; ++j) {
    int i = t * 16 + j;
    float v = mu[i];
    sum += v;
    if (v < mnv) { mnv = v; mni = i; }
    if (v == 0.f) zf = 1;
  }
  sum = wave_sum(sum);
  wave_minidx(mnv, mni);
#pragma unroll
  for (int o = 32; o > 0; o >>= 1) zf |= __shfl_down(zf, o, 64);
  if (lane == 0) { ssum[w] = sum; swv[w] = mnv; swi[w] = mni; szf[w] = zf; }
  __syncthreads();
  if (t == 0) {
    float muSum = ssum[0] + ssum[1] + ssum[2] + ssum[3];
    float a = swv[0]; int li = swi[0];
    for (int i = 1; i < 4; ++i)
      if (swv[i] < a || (swv[i] == a && swi[i] < li)) { a = swv[i]; li = swi[i]; }
    int anyz = szf[0] | szf[1] | szf[2] | szf[3];
    float muMean = muSum / 4096.f;
    float internal_sim = s_res[0];
    int iflat = s_resi[0];
    float sim_cand = s_res[1];
    int msi = s_resi[1];
    int branch, i1 = -1, i2 = -1;
    float u1 = 0.f, u2 = 0.f;
    if (anyz) {                       // not_full
      branch = 0; i1 = li; u1 = muMean + 1e-5f;
    } else if (sim_cand > 0.98f) {    // merge_with_candidate
      branch = 1; i1 = msi; u1 = (mu[msi] + muMean) * 0.5f;
    } else if (internal_sim > 0.98f) {  // do_pair_merge
      branch = 2; i1 = iflat / MSZ; i2 = iflat - (iflat / MSZ) * MSZ;
      float o1 = mu[i1], o2 = mu[i2];
      u1 = (o1 + o2) * 0.5f;
      u2 = (muSum - o1 + u1) / 4096.f + 1e-5f;  // torch recomputes mean after idx1 write
    } else {                          // replace_weakest
      if (cnorm[0] > mnorm[li]) { branch = 0; i1 = li; u1 = muMean + 1e-5f; }
      else branch = 4;
    }
    dec_i[0] = branch; dec_i[1] = i1; dec_i[2] = i2;
    dec_f[0] = u1; dec_f[1] = u2;
  }
}

// ---------------- K12: write m_memory output ----------------
__global__ void k_write_m(const float* __restrict__ m, const float* __restrict__ out_s,
                          const int* __restrict__ best, const int* __restrict__ dec_i,
                          float* __restrict__ out_m) {
  __shared__ float sred[4];
  int row = blockIdx.x, t = threadIdx.x, lane = t & 63, w = t >> 6;
  int branch = dec_i[0], i1 = dec_i[1], i2 = dec_i[2];
  int mode = 0;  // copy
  if ((branch == 0 && row == i1) || (branch == 2 && row == i2)) mode = 1;  // candidate
  else if (branch == 1 && row == i1) mode = 2;                             // merge w/ candidate
  else if (branch == 2 && row == i1) mode = 3;                             // pair merge
  f32x4* dst = (f32x4*)(out_m + (size_t)row * DIMV);
  if (mode == 0) {
    dst[t] = ((const f32x4*)(m + (size_t)row * DIMV))[t];
  } else if (mode == 1) {
    dst[t] = ((const f32x4*)(out_s + (size_t)best[0] * DIMV))[t];
  } else {
    f32x4 a = ((const f32x4*)(m + (size_t)row * DIMV))[t];
    f32x4 bb = (mode == 2) ? ((const f32x4*)(out_s + (size_t)best[0] * DIMV))[t]
                           : ((const f32x4*)(m + (size_t)i2 * DIMV))[t];
    f32x4 v = (a + bb) * 0.5f;
    float ss = v.x * v.x + v.y * v.y + v.z * v.z + v.w * v.w;
    ss = wave_sum(ss);
    if (lane == 0) sred[w] = ss;
    __syncthreads();
    float nrm = fmaxf(sqrtf(sred[0] + sred[1] + sred[2] + sred[3]), 1e-12f);
    dst[t] = v / nrm;
  }
}

// ---------------- K13: write m_utility output ----------------
__global__ void k_write_mu(const float* __restrict__ mu, const int* __restrict__ dec_i,
                           const float* __restrict__ dec_f, float* __restrict__ out_mu) {
  int i = blockIdx.x * 256 + threadIdx.x;
  float v = mu[i];
  int branch = dec_i[0];
  if (branch != 4 && i == dec_i[1]) v = dec_f[0];
  if (branch == 2 && i == dec_i[2]) v = dec_f[1];
  out_mu[i] = v;
}

// ---------------- K14: L-tier scalars + l_utility output ----------------
__global__ void k_ltier(const float* __restrict__ out_mu, const float* __restrict__ lu,
                        float* __restrict__ out_lu, int* __restrict__ wsi) {
  __shared__ float swv[4];
  __shared__ int swi[4];
  __shared__ float ssum[4];
  __shared__ float s_mean;
  __shared__ int s_lj;
  int t = threadIdx.x, lane = t & 63, w = t >> 6;
  // mi = argmax(updated m_utility), first occurrence
  float bv = -3.402823466e38f;
  int bidx = 0x7FFFFFFF;
#pragma unroll
  for (int j = 0; j < 16; ++j) {
    int i = t * 16 + j;
    float v = out_mu[i];
    if (v > bv) { bv = v; bidx = i; }
  }
  wave_maxidx(bv, bidx);
  if (lane == 0) { swv[w] = bv; swi[w] = bidx; }
  __syncthreads();
  if (t == 0) {
    float a = swv[0]; int ai = swi[0];
    for (int i = 1; i < 4; ++i)
      if (swv[i] > a || (swv[i] == a && swi[i] < ai)) { a = swv[i]; ai = swi[i]; }
    wsi[1] = ai;
  }
  __syncthreads();
  // lj = argmin(l_utility) first occurrence; mean(l_utility)
  float mnv = 3.402823466e38f, sum = 0.f;
  int mni = 0x7FFFFFFF;
#pragma unroll
  for (int j = 0; j < 32; ++j) {
    int i = t * 32 + j;
    float v = lu[i];
    sum += v;
    if (v < mnv) { mnv = v; mni = i; }
  }
  sum = wave_sum(sum);
  wave_minidx(mnv, mni);
  if (lane == 0) { swv[w] = mnv; swi[w] = mni; ssum[w] = sum; }
  __syncthreads();
  if (t == 0) {
    float a = swv[0]; int ai = swi[0];
    for (int i = 1; i < 4; ++i)
      if (swv[i] < a || (swv[i] == a && swi[i] < ai)) { a = swv[i]; ai = swi[i]; }
    s_lj = ai;
    s_mean = (ssum[0] + ssum[1] + ssum[2] + ssum[3]) / 8192.f;
    wsi[0] = ai;
  }
  __syncthreads();
  int lj = s_lj;
  float lmv = s_mean;
#pragma unroll
  for (int j = 0; j < 32; ++j) {
    int i = t * 32 + j;
    out_lu[i] = (i == lj) ? lmv : lu[i];
  }
}

// ---------------- K15: write l_memory output (erases scratch) ----------------
__global__ void k_write_l(const float* __restrict__ l_memory, const float* __restrict__ out_m,
                          const int* __restrict__ wsi, float* __restrict__ out_l) {
  int row = blockIdx.x, t = threadIdx.x;
  int lj = wsi[0], mi = wsi[1];
  f32x4 v = ((const f32x4*)(l_memory + (size_t)row * DIMV))[t];
  if (row == lj) {
    f32x4 mv = ((const f32x4*)(out_m + (size_t)mi * DIMV))[t];
    v = v * 0.9f + mv * 0.1f;
  }
  ((f32x4*)(out_l + (size_t)row * DIMV))[t] = v;
}

extern "C" void kernel_launch(void* const* d_in, const int* in_sizes, int n_in,
                              void* d_out, int out_size, void* d_ws, size_t ws_size,
                              hipStream_t stream) {
  const float* cand = (const float*)d_in[0];
  const float* s_memory = (const float*)d_in[1];
  const float* m_memory = (const float*)d_in[2];
  const float* l_memory = (const float*)d_in[3];
  const float* m_utility = (const float*)d_in[4];
  const float* l_utility = (const float*)d_in[5];
  const float* wq = (const float*)d_in[6];
  const float* bq = (const float*)d_in[7];
  const float* wk = (const float*)d_in[8];
  const float* bk = (const float*)d_in[9];
  const int* s_ptr = (const int*)d_in[10];

  float* out = (float*)d_out;
  float* out_s = out + OUT_S;
  float* out_m = out + OUT_M;
  float* out_l = out + OUT_L;
  float* out_mu = out + OUT_MU;
  float* out_lu = out + OUT_LU;
  float* out_sptr = out + OUT_SPTR;

  float* lsc = out_l;  // scratch region: consumed before K15 overwrites it
  unsigned short* mb = (unsigned short*)(lsc + SC_BF16);
  float* norms = lsc + SC_NORMS;
  int* topidx = (int*)(lsc + SC_TOPIDX);
  float* lpart = lsc + SC_LPART;
  float* lmean = lsc + SC_LMEAN;
  float* qv = lsc + SC_Q;
  float* rpart = lsc + SC_RPART;
  float* rv = lsc + SC_R;
  float* cs = lsc + SC_CSCAL;
  float* logits = lsc + SC_LOGITS;
  int* best = (int*)(lsc + SC_BEST);
  float* cnorm = lsc + SC_BEST + 1;
  float* mnorm = lsc + SC_MNORM;
  float* sims = lsc + SC_SIMS;
  float* pv = lsc + SC_PPV;
  int* pidx = (int*)(lsc + SC_PPI);
  int* dec_i = (int*)(lsc + SC_DEC);
  float* dec_f = lsc + SC_DEC + 4;
  int* wsi = (int*)d_ws;  // only 8 bytes of d_ws used (read after scratch is dead)

  k_cand_norms<<<4096, 256, 0, stream>>>(cand, norms);
  k_topk<<<1, 1024, 0, stream>>>(norms, topidx);
  k_write_s<<<512, 256, 0, stream>>>(cand, s_memory, topidx, s_ptr, out_s, out_sptr);
  k_lpart<<<128, 256, 0, stream>>>(l_memory, lpart);
  k_lmean<<<1, 256, 0, stream>>>(lpart, lmean);
  k_q<<<256, 256, 0, stream>>>(wq, bq, lmean, qv);
  k_rpart<<<128, 256, 0, stream>>>(wk, qv, rpart);
  k_rfinal<<<1, 256, 0, stream>>>(rpart, rv);
  k_cscal<<<1, 256, 0, stream>>>(bk, qv, cs);
  k_logits<<<128, 256, 0, stream>>>(out_s, rv, cs, logits);
  k_argmax_logits<<<1, 256, 0, stream>>>(logits, out_s, best, cnorm);
  k_msims<<<1024, 256, 0, stream>>>(m_memory, out_s, best, cnorm, mb, mnorm, sims);
  k_pairmax<<<528, 256, 0, stream>>>(mb, mnorm, pv, pidx);
  k_decide<<<1, 256, 0, stream>>>(pv, pidx, sims, m_utility, mnorm, cnorm, 528, dec_i, dec_f);
  k_write_m<<<4096, 256, 0, stream>>>(m_memory, out_s, best, dec_i, out_m);
  k_write_mu<<<16, 256, 0, stream>>>(m_utility, dec_i, dec_f, out_mu);
  k_ltier<<<1, 256, 0, stream>>>(out_mu, l_utility, out_lu, wsi);
  k_write_l<<<8192, 256, 0, stream>>>(l_memory, out_m, wsi, out_l);
}

// Round 2
// 327.035 us; speedup vs baseline: 1.0155x; 1.0155x over previous
//
#include <hip/hip_runtime.h>

#define DIMV 1024
#define SSZ 512
#define MSZ 4096
#define LSZ 8192
#define KPROM 128
#define NCAND 16384
#define NPAIR 1056  // 128x64 tiles over strict lower triangle: sum_{bi<32} (2bi+2)

typedef __attribute__((ext_vector_type(4))) float f32x4;
typedef __attribute__((ext_vector_type(4))) unsigned int u32x4;
typedef __attribute__((ext_vector_type(4))) unsigned short u16x4;
typedef __attribute__((ext_vector_type(8))) __bf16 bf16x8;

// ---------------- output layout (float element offsets) ----------------
#define OUT_S 0ull
#define OUT_M 524288ull
#define OUT_L 4718592ull
#define OUT_MU 13107200ull
#define OUT_LU 13111296ull
#define OUT_SPTR 13119488ull

// ---- scratch inside out_l region (8,388,608 floats; erased last by kI) ----
#define SC_BF16 0ull          // 4096x1024 bf16 (2,097,152 float slots)
#define SC_NORMS 2100000ull   // 16384
#define SC_TOPIDX 2117000ull  // 128 ints
#define SC_LPART 2120000ull   // 128*1024
#define SC_RV 2260000ull      // 1024 (memset to 0)
#define SC_LMEAN 2262000ull   // 1024
#define SC_Q 2264000ull       // 1024
#define SC_LOGITS 2413000ull  // 512
#define SC_BEST 2414000ull    // [0] int best_s_idx, [1] float cnorm
#define SC_MNORM 2415000ull   // 4096
#define SC_SIMS 2420000ull    // 4096
#define SC_PPV 2425000ull     // 1056 partial max vals
#define SC_PPI 2427000ull     // 1056 partial max flat idx

__device__ __forceinline__ float wave_sum(float v) {
#pragma unroll
  for (int o = 32; o > 0; o >>= 1) v += __shfl_down(v, o, 64);
  return v;
}
__device__ __forceinline__ void wave_maxidx(float& v, int& i) {
#pragma unroll
  for (int o = 32; o > 0; o >>= 1) {
    float ov = __shfl_down(v, o, 64);
    int oi = __shfl_down(i, o, 64);
    if (ov > v || (ov == v && oi < i)) { v = ov; i = oi; }
  }
}
__device__ __forceinline__ void wave_minidx(float& v, int& i) {
#pragma unroll
  for (int o = 32; o > 0; o >>= 1) {
    float ov = __shfl_down(v, o, 64);
    int oi = __shfl_down(i, o, 64);
    if (ov < v || (ov == v && oi < i)) { v = ov; i = oi; }
  }
}
__device__ __forceinline__ unsigned short f2bf(float x) {  // RNE float->bf16
  unsigned u = __float_as_uint(x);
  return (unsigned short)((u + 0x7FFFu + ((u >> 16) & 1u)) >> 16);
}

// ============ kA: cand norms (4096 blk) + lpart (128 blk) + bf16 M + mnorm (1024 blk) ============
__global__ void kA(const float* __restrict__ cand, const float* __restrict__ l_memory,
                   const float* __restrict__ m, float* __restrict__ norms,
                   float* __restrict__ lpart, unsigned short* __restrict__ mb,
                   float* __restrict__ mnorm) {
  int b = blockIdx.x, t = threadIdx.x, lane = t & 63, w = t >> 6;
  if (b < 4096) {  // candidate row norms, 4 rows/block
    int row = b * 4 + w;
    const f32x4* p = (const f32x4*)(cand + (size_t)row * DIMV);
    float s = 0.f;
#pragma unroll
    for (int c = 0; c < 4; ++c) {
      f32x4 v = p[c * 64 + lane];
      s += v.x * v.x + v.y * v.y + v.z * v.z + v.w * v.w;
    }
    s = wave_sum(s);
    if (lane == 0) norms[row] = sqrtf(s);
  } else if (b < 4224) {  // l column partial sums, 64 rows/block
    int bb = b - 4096;
    f32x4 a = {0.f, 0.f, 0.f, 0.f};
    const f32x4* base = (const f32x4*)(l_memory + (size_t)bb * 64 * DIMV);
    for (int r = 0; r < 64; ++r) a += base[r * 256 + t];
    ((f32x4*)(lpart + (size_t)bb * DIMV))[t] = a;
  } else {  // m -> bf16 + row norms, 4 rows/block
    int row = (b - 4224) * 4 + w;
    const f32x4* mp = (const f32x4*)(m + (size_t)row * DIMV);
    float ss = 0.f;
#pragma unroll
    for (int c = 0; c < 4; ++c) {
      int i = c * 64 + lane;
      f32x4 v = mp[i];
      ss += v.x * v.x + v.y * v.y + v.z * v.z + v.w * v.w;
      u16x4 h;
      h.x = f2bf(v.x); h.y = f2bf(v.y); h.z = f2bf(v.z); h.w = f2bf(v.w);
      ((u16x4*)(mb + (size_t)row * DIMV))[i] = h;
    }
    ss = wave_sum(ss);
    if (lane == 0) mnorm[row] = sqrtf(ss);
  }
}

// ============ kT: blk0 = exact stable top-128 (8-bit radix), blk1 = lmean final ============
__device__ int scan_excl_1024(int v, int* sh, int* total) {
  int t = threadIdx.x;
  sh[t] = v;
  __syncthreads();
  for (int o = 1; o < 1024; o <<= 1) {
    int x = (t >= o) ? sh[t - o] : 0;
    __syncthreads();
    sh[t] += x;
    __syncthreads();
  }
  int incl = sh[t];
  *total = sh[1023];
  __syncthreads();
  return incl - v;
}

__global__ void kT(const float* __restrict__ norms, int* __restrict__ topidx,
                   const float* __restrict__ lpart, float* __restrict__ lmean) {
  int t = threadIdx.x;
  if (blockIdx.x == 1) {  // lmean: reduce 128 partials per column
    float s = 0.f;
    for (int p = 0; p < 128; ++p) s += lpart[(size_t)p * DIMV + t];
    lmean[t] = s * (1.f / 8192.f);
    return;
  }
  __shared__ int sh[1024];
  __shared__ int hist[256];
  __shared__ unsigned s_selkey[KPROM];
  __shared__ int s_selidx[KPROM];
  __shared__ int s_digit, s_sub;
  unsigned key[16];
#pragma unroll
  for (int j = 0; j < 16; ++j) key[j] = __float_as_uint(norms[t * 16 + j]);  // >0: bits monotone

  unsigned prefix = 0, himask = 0;
  int remaining = KPROM;
  for (int p = 24; p >= 0; p -= 8) {
    if (t < 256) hist[t] = 0;
    __syncthreads();
#pragma unroll
    for (int j = 0; j < 16; ++j)
      if ((key[j] & himask) == prefix) atomicAdd(&hist[(key[j] >> p) & 255], 1);
    __syncthreads();
    if (t < 256) sh[t] = hist[t];
    __syncthreads();
    for (int o = 1; o < 256; o <<= 1) {  // suffix-inclusive sum
      int x = (t < 256 && t + o < 256) ? sh[t + o] : 0;
      __syncthreads();
      if (t < 256) sh[t] += x;
      __syncthreads();
    }
    if (t < 256) {
      int sfex = (t < 255) ? sh[t + 1] : 0;  // count of keys with strictly greater digit
      if (sfex < remaining && remaining <= sh[t]) { s_digit = t; s_sub = sfex; }
    }
    __syncthreads();
    prefix |= ((unsigned)s_digit) << p;
    remaining -= s_sub;
    himask |= (0xFFu << p);
    __syncthreads();
  }
  unsigned T = prefix;  // exact 128th-largest key

  int cgt = 0, ceq = 0;
#pragma unroll
  for (int j = 0; j < 16; ++j) { cgt += (key[j] > T); ceq += (key[j] == T); }
  int total_gt, total_eq;
  int sgt = scan_excl_1024(cgt, sh, &total_gt);
  int seq = scan_excl_1024(ceq, sh, &total_eq);
  int need_eq = KPROM - total_gt;
  int g = sgt, e = seq;
#pragma unroll
  for (int j = 0; j < 16; ++j) {
    if (key[j] > T) { s_selkey[g] = key[j]; s_selidx[g] = t * 16 + j; ++g; }
    else if (key[j] == T) {
      if (e < need_eq) { s_selkey[total_gt + e] = key[j]; s_selidx[total_gt + e] = t * 16 + j; }
      ++e;
    }
  }
  __syncthreads();
  if (t < KPROM) {  // stable rank: value desc, index asc == lax.top_k
    unsigned mk = s_selkey[t];
    int mi = s_selidx[t];
    int rank = 0;
    for (int q2 = 0; q2 < KPROM; ++q2) {
      unsigned qk = s_selkey[q2];
      int qi = s_selidx[q2];
      rank += (qk > mk || (qk == mk && qi < mi)) ? 1 : 0;
    }
    topidx[rank] = mi;
  }
}

// ============ kB: write_s (512 blk) + q = wq@lmean + bq (256 blk) ============
__global__ void kB(const float* __restrict__ cand, const float* __restrict__ s_memory,
                   const int* __restrict__ topidx, const int* __restrict__ s_ptr,
                   const float* __restrict__ wq, const float* __restrict__ bq,
                   const float* __restrict__ lmean, float* __restrict__ out_s,
                   float* __restrict__ out_sptr, float* __restrict__ qv) {
  int b = blockIdx.x, t = threadIdx.x;
  if (b < 512) {
    int sp = s_ptr[0];
    int k = (b - sp + SSZ) & (SSZ - 1);
    const float* src = (k < KPROM) ? (cand + (size_t)topidx[k] * DIMV) : (s_memory + (size_t)b * DIMV);
    ((f32x4*)(out_s + (size_t)b * DIMV))[t] = ((const f32x4*)src)[t];
    if (b == 0 && t == 0) out_sptr[0] = (float)((sp + KPROM) % SSZ);
  } else {
    int lane = t & 63, w = t >> 6;
    int d = (b - 512) * 4 + w;
    const f32x4* row = (const f32x4*)(wq + (size_t)d * DIMV);
    const f32x4* lm = (const f32x4*)lmean;
    float s = 0.f;
#pragma unroll
    for (int c = 0; c < 4; ++c) {
      f32x4 a = row[c * 64 + lane], bb = lm[c * 64 + lane];
      s += a.x * bb.x + a.y * bb.y + a.z * bb.z + a.w * bb.w;
    }
    s = wave_sum(s);
    if (lane == 0) qv[d] = s + bq[d];
  }
}

// ============ kC: rv += q[d] * wk[d][:] (atomic, rv pre-zeroed) ============
__global__ void kC(const float* __restrict__ wk, const float* __restrict__ qv,
                   float* __restrict__ rv) {
  int b = blockIdx.x, t = threadIdx.x;
  f32x4 a = {0.f, 0.f, 0.f, 0.f};
  for (int r = 0; r < 8; ++r) {
    float qd = qv[b * 8 + r];
    f32x4 v = ((const f32x4*)(wk + (size_t)(b * 8 + r) * DIMV))[t];
    a += v * qd;
  }
  atomicAdd(&rv[t * 4 + 0], a.x);
  atomicAdd(&rv[t * 4 + 1], a.y);
  atomicAdd(&rv[t * 4 + 2], a.z);
  atomicAdd(&rv[t * 4 + 3], a.w);
}

// ============ kD: logits[s] = s_mem[s].rv  (bk.q shift + 1/sqrt(D) scale are argmax-invariant) ============
__global__ void kD(const float* __restrict__ out_s, const float* __restrict__ rv,
                   float* __restrict__ logits) {
  int lane = threadIdx.x & 63, w = threadIdx.x >> 6;
  int srow = blockIdx.x * 4 + w;
  const f32x4* a = (const f32x4*)(out_s + (size_t)srow * DIMV);
  const f32x4* b = (const f32x4*)rv;
  float s = 0.f;
#pragma unroll
  for (int c = 0; c < 4; ++c) {
    f32x4 x = a[c * 64 + lane], y = b[c * 64 + lane];
    s += x.x * y.x + x.y * y.y + x.z * y.z + x.w * y.w;
  }
  s = wave_sum(s);
  if (lane == 0) logits[srow] = s;
}

// ============ kE: best = argmax(logits); cnorm = ||s_mem[best]|| ============
__global__ void kE(const float* __restrict__ logits, const float* __restrict__ out_s,
                   int* __restrict__ best, float* __restrict__ cnorm) {
  __shared__ float swv[4];
  __shared__ int swi[4];
  int t = threadIdx.x, lane = t & 63, w = t >> 6;
  float v0 = logits[t], v1 = logits[t + 256];
  float bv;
  int bidx;
  if (v1 > v0) { bv = v1; bidx = t + 256; } else { bv = v0; bidx = t; }
  wave_maxidx(bv, bidx);
  if (lane == 0) { swv[w] = bv; swi[w] = bidx; }
  __syncthreads();
  if (t == 0) {
    float a = swv[0]; int ai = swi[0];
    for (int i = 1; i < 4; ++i)
      if (swv[i] > a || (swv[i] == a && swi[i] < ai)) { a = swv[i]; ai = swi[i]; }
    best[0] = ai;
  }
  __syncthreads();
  int bi = best[0];
  f32x4 c4 = ((const f32x4*)(out_s + (size_t)bi * DIMV))[t];
  float s = c4.x * c4.x + c4.y * c4.y + c4.z * c4.z + c4.w * c4.w;
  s = wave_sum(s);
  __syncthreads();
  if (lane == 0) swv[w] = s;
  __syncthreads();
  if (t == 0) cnorm[0] = sqrtf(swv[0] + swv[1] + swv[2] + swv[3]);
}

// ============ kG: pairmax (1056 blk, 128x64 tiles) + sims vs candidate (1024 blk) ============
__global__ __launch_bounds__(256, 4) void kG(const unsigned short* __restrict__ mb,
                                             const float* __restrict__ mnorm,
                                             const float* __restrict__ m,
                                             const float* __restrict__ out_s,
                                             const int* __restrict__ best,
                                             const float* __restrict__ cnorm,
                                             float* __restrict__ pv, int* __restrict__ pidx,
                                             float* __restrict__ sims) {
  int b = blockIdx.x, t = threadIdx.x, lane = t & 63, w = t >> 6;
  if (b >= NPAIR) {  // sims: fp32 dot vs candidate, 4 rows/block
    int row = (b - NPAIR) * 4 + w;
    const f32x4* mp = (const f32x4*)(m + (size_t)row * DIMV);
    const f32x4* cp = (const f32x4*)(out_s + (size_t)best[0] * DIMV);
    float sd = 0.f;
#pragma unroll
    for (int c = 0; c < 4; ++c) {
      int i = c * 64 + lane;
      f32x4 v = mp[i], u = cp[i];
      sd += v.x * u.x + v.y * u.y + v.z * u.z + v.w * u.w;
    }
    sd = wave_sum(sd);
    if (lane == 0) sims[row] = sd / (fmaxf(mnorm[row], 1e-12f) * fmaxf(cnorm[0], 1e-12f));
    return;
  }
  __shared__ unsigned short At[128 * 72];  // +pad: 144B row stride -> <=2-way (free) on b128
  __shared__ unsigned short Bt[64 * 72];
  __shared__ float spv[4];
  __shared__ int spi[4];
  int bi = (int)((sqrtf(4.f * (float)b + 1.f) - 1.f) * 0.5f);
  while (bi * bi + bi > b) --bi;
  while ((bi + 1) * (bi + 1) + (bi + 1) <= b) ++bi;
  int bj = b - (bi * bi + bi);
  int wr = w >> 1, wc = w & 1;
  int rl = lane & 15, kq = (lane >> 4) * 8, riq = (lane >> 4) * 4;
  int rowA0 = bi * 128, rowB0 = bj * 64;

  f32x4 acc[4][2];
  f32x4 z = {0.f, 0.f, 0.f, 0.f};
#pragma unroll
  for (int i = 0; i < 4; ++i) { acc[i][0] = z; acc[i][1] = z; }

  for (int kc = 0; kc < DIMV; kc += 64) {
    __syncthreads();
#pragma unroll
    for (int c = 0; c < 6; ++c) {  // 1536 x 16B chunks: A 1024, B 512
      int chunk = c * 256 + t;
      if (chunk < 1024) {
        int r = chunk >> 3, g = chunk & 7;
        u32x4 va = *(const u32x4*)(mb + (size_t)(rowA0 + r) * DIMV + kc + g * 8);
        *(u32x4*)(At + r * 72 + g * 8) = va;
      } else {
        int c3 = chunk - 1024;
        int r = c3 >> 3, g = c3 & 7;
        u32x4 vb = *(const u32x4*)(mb + (size_t)(rowB0 + r) * DIMV + kc + g * 8);
        *(u32x4*)(Bt + r * 72 + g * 8) = vb;
      }
    }
    __syncthreads();
#pragma unroll
    for (int ks = 0; ks < 64; ks += 32) {
      bf16x8 af[4], bfv[2];
#pragma unroll
      for (int ti = 0; ti < 4; ++ti)
        af[ti] = *(const bf16x8*)(At + (wr * 64 + ti * 16 + rl) * 72 + ks + kq);
#pragma unroll
      for (int tj = 0; tj < 2; ++tj)
        bfv[tj] = *(const bf16x8*)(Bt + (wc * 32 + tj * 16 + rl) * 72 + ks + kq);
#pragma unroll
      for (int ti = 0; ti < 4; ++ti)
#pragma unroll
        for (int tj = 0; tj < 2; ++tj)
          acc[ti][tj] = __builtin_amdgcn_mfma_f32_16x16x32_bf16(af[ti], bfv[tj], acc[ti][tj], 0, 0, 0);
    }
  }
  float ni[16], nj[2];
#pragma unroll
  for (int ti = 0; ti < 4; ++ti)
#pragma unroll
    for (int r = 0; r < 4; ++r)
      ni[ti * 4 + r] = fmaxf(mnorm[rowA0 + wr * 64 + ti * 16 + riq + r], 1e-12f);
#pragma unroll
  for (int tj = 0; tj < 2; ++tj)
    nj[tj] = fmaxf(mnorm[rowB0 + wc * 32 + tj * 16 + rl], 1e-12f);

  float bv = -3.402823466e38f;
  int bidx = 0x7FFFFFFF;
#pragma unroll
  for (int ti = 0; ti < 4; ++ti)
#pragma unroll
    for (int tj = 0; tj < 2; ++tj)
#pragma unroll
      for (int r = 0; r < 4; ++r) {
        int gi = rowA0 + wr * 64 + ti * 16 + riq + r;  // C/D row = quad*4+reg
        int gj = rowB0 + wc * 32 + tj * 16 + rl;       // C/D col = lane&15
        if (gi > gj) {
          float s = acc[ti][tj][r] / (ni[ti * 4 + r] * nj[tj]);
          int fi = gi * MSZ + gj;
          if (s > bv || (s == bv && fi < bidx)) { bv = s; bidx = fi; }
        }
      }
  wave_maxidx(bv, bidx);
  if (lane == 0) { spv[w] = bv; spi[w] = bidx; }
  __syncthreads();
  if (t == 0) {
    float a = spv[0]; int ai = spi[0];
    for (int i = 1; i < 4; ++i)
      if (spv[i] > a || (spv[i] == a && spi[i] < ai)) { a = spv[i]; ai = spi[i]; }
    pv[b] = a;
    pidx[b] = ai;
  }
}

// ============ kH: decide + out_mu + ltier + export control to d_ws (1 blk x 1024) ============
__global__ void kH(const float* __restrict__ pv, const int* __restrict__ pidx,
                   const float* __restrict__ sims, const float* __restrict__ mu,
                   const float* __restrict__ mnorm, const float* __restrict__ cnorm,
                   const int* __restrict__ best, const float* __restrict__ lu,
                   float* __restrict__ out_mu, float* __restrict__ out_lu,
                   int* __restrict__ ws) {
  __shared__ float swv[16];
  __shared__ int swi[16];
  __shared__ float ssum[16];
  __shared__ int szf[16];
  __shared__ float s_res[2];
  __shared__ int s_resi[2];
  __shared__ int s_branch, s_i1, s_i2, s_lj;
  __shared__ float s_u1, s_u2, s_lmean;
  int t = threadIdx.x, lane = t & 63, w = t >> 6;

  // A: internal pairwise max over 1056 block-partials
  float bv = -3.402823466e38f;
  int bidx = 0x7FFFFFFF;
  for (int i = t; i < NPAIR; i += 1024) {
    float v = pv[i];
    int fi = pidx[i];
    if (v > bv || (v == bv && fi < bidx)) { bv = v; bidx = fi; }
  }
  wave_maxidx(bv, bidx);
  if (lane == 0) { swv[w] = bv; swi[w] = bidx; }
  __syncthreads();
  if (t == 0) {
    float a = swv[0]; int ai = swi[0];
    for (int i = 1; i < 16; ++i)
      if (swv[i] > a || (swv[i] == a && swi[i] < ai)) { a = swv[i]; ai = swi[i]; }
    s_res[0] = a; s_resi[0] = ai;
  }
  __syncthreads();

  // B: argmax(sims), first occurrence
  bv = -3.402823466e38f;
  bidx = 0x7FFFFFFF;
#pragma unroll
  for (int j = 0; j < 4; ++j) {
    int i = t * 4 + j;
    float v = sims[i];
    if (v > bv) { bv = v; bidx = i; }
  }
  wave_maxidx(bv, bidx);
  if (lane == 0) { swv[w] = bv; swi[w] = bidx; }
  __syncthreads();
  if (t == 0) {
    float a = swv[0]; int ai = swi[0];
    for (int i = 1; i < 16; ++i)
      if (swv[i] > a || (swv[i] == a && swi[i] < ai)) { a = swv[i]; ai = swi[i]; }
    s_res[1] = a; s_resi[1] = ai;
  }
  __syncthreads();

  // C: mu stats
  float muv[4];
  float sum = 0.f, mnv = 3.402823466e38f;
  int mni = 0x7FFFFFFF, zf = 0;
#pragma unroll
  for (int j = 0; j < 4; ++j) {
    int i = t * 4 + j;
    float v = mu[i];
    muv[j] = v;
    sum += v;
    if (v < mnv) { mnv = v; mni = i; }
    if (v == 0.f) zf = 1;
  }
  sum = wave_sum(sum);
  wave_minidx(mnv, mni);
#pragma unroll
  for (int o = 32; o > 0; o >>= 1) zf |= __shfl_down(zf, o, 64);
  if (lane == 0) { ssum[w] = sum; swv[w] = mnv; swi[w] = mni; szf[w] = zf; }
  __syncthreads();
  if (t == 0) {
    float muSum = 0.f;
    int anyz = 0;
    float a = swv[0]; int li = swi[0];
    for (int i = 0; i < 16; ++i) {
      muSum += ssum[i];
      anyz |= szf[i];
      if (i > 0 && (swv[i] < a || (swv[i] == a && swi[i] < li))) { a = swv[i]; li = swi[i]; }
    }
    float muMean = muSum / 4096.f;
    float internal_sim = s_res[0];
    int iflat = s_resi[0];
    float sim_cand = s_res[1];
    int msi = s_resi[1];
    int branch, i1 = -1, i2 = -1;
    float u1 = 0.f, u2 = 0.f;
    if (anyz) {
      branch = 0; i1 = li; u1 = muMean + 1e-5f;
    } else if (sim_cand > 0.98f) {
      branch = 1; i1 = msi; u1 = (mu[msi] + muMean) * 0.5f;
    } else if (internal_sim > 0.98f) {
      branch = 2; i1 = iflat / MSZ; i2 = iflat - (iflat / MSZ) * MSZ;
      float o1 = mu[i1], o2 = mu[i2];
      u1 = (o1 + o2) * 0.5f;
      u2 = (muSum - o1 + u1) / 4096.f + 1e-5f;  // mean recomputed after idx1 write
    } else {
      if (cnorm[0] > mnorm[li]) { branch = 0; i1 = li; u1 = muMean + 1e-5f; }
      else branch = 4;
    }
    s_branch = branch; s_i1 = i1; s_i2 = i2; s_u1 = u1; s_u2 = u2;
    ws[2] = branch; ws[3] = i1; ws[4] = i2; ws[5] = best[0];
  }
  __syncthreads();

  // D: write out_mu + argmax of updated mu (first occurrence)
  int branch = s_branch, i1 = s_i1, i2 = s_i2;
  float u1 = s_u1, u2 = s_u2;
  bv = -3.402823466e38f;
  bidx = 0x7FFFFFFF;
#pragma unroll
  for (int j = 0; j < 4; ++j) {
    int i = t * 4 + j;
    float v = muv[j];
    if (branch != 4 && i == i1) v = u1;
    if (branch == 2 && i == i2) v = u2;
    out_mu[i] = v;
    if (v > bv) { bv = v; bidx = i; }
  }
  wave_maxidx(bv, bidx);
  __syncthreads();
  if (lane == 0) { swv[w] = bv; swi[w] = bidx; }
  __syncthreads();
  if (t == 0) {
    float a = swv[0]; int ai = swi[0];
    for (int i = 1; i < 16; ++i)
      if (swv[i] > a || (swv[i] == a && swi[i] < ai)) { a = swv[i]; ai = swi[i]; }
    ws[1] = ai;  // mi
  }

  // E: ltier — lj = argmin(lu) first occurrence, mean(lu) of pre-write values
  float luv[8];
  sum = 0.f; mnv = 3.402823466e38f; mni = 0x7FFFFFFF;
#pragma unroll
  for (int j = 0; j < 8; ++j) {
    int i = t * 8 + j;
    float v = lu[i];
    luv[j] = v;
    sum += v;
    if (v < mnv) { mnv = v; mni = i; }
  }
  sum = wave_sum(sum);
  wave_minidx(mnv, mni);
  __syncthreads();
  if (lane == 0) { swv[w] = mnv; swi[w] = mni; ssum[w] = sum; }
  __syncthreads();
  if (t == 0) {
    float a = swv[0]; int ai = swi[0];
    float ls = 0.f;
    for (int i = 0; i < 16; ++i) {
      ls += ssum[i];
      if (i > 0 && (swv[i] < a || (swv[i] == a && swi[i] < ai))) { a = swv[i]; ai = swi[i]; }
    }
    s_lj = ai;
    s_lmean = ls / 8192.f;
    ws[0] = ai;
  }
  __syncthreads();
  int lj = s_lj;
  float lmv = s_lmean;
#pragma unroll
  for (int j = 0; j < 8; ++j) {
    int i = t * 8 + j;
    out_lu[i] = (i == lj) ? lmv : luv[j];
  }
}

// ============ kI: write_m (4096 blk) + write_l (8192 blk, out_m[mi] recomputed inline) ============
__global__ void kI(const float* __restrict__ m, const float* __restrict__ l_memory,
                   const float* __restrict__ out_s, const int* __restrict__ ws,
                   float* __restrict__ out_m, float* __restrict__ out_l) {
  __shared__ float sred[4];
  int b = blockIdx.x, t = threadIdx.x, lane = t & 63, w = t >> 6;
  int lj = ws[0], mi = ws[1], branch = ws[2], i1 = ws[3], i2 = ws[4], best = ws[5];
  if (b < 4096) {
    int row = b;
    int mode = 0;
    if ((branch == 0 && row == i1) || (branch == 2 && row == i2)) mode = 1;
    else if (branch == 1 && row == i1) mode = 2;
    else if (branch == 2 && row == i1) mode = 3;
    f32x4* dst = (f32x4*)(out_m + (size_t)row * DIMV);
    if (mode == 0) {
      dst[t] = ((const f32x4*)(m + (size_t)row * DIMV))[t];
    } else if (mode == 1) {
      dst[t] = ((const f32x4*)(out_s + (size_t)best * DIMV))[t];
    } else {
      f32x4 a = ((const f32x4*)(m + (size_t)row * DIMV))[t];
      f32x4 bb = (mode == 2) ? ((const f32x4*)(out_s + (size_t)best * DIMV))[t]
                             : ((const f32x4*)(m + (size_t)i2 * DIMV))[t];
      f32x4 v = (a + bb) * 0.5f;
      float ss = v.x * v.x + v.y * v.y + v.z * v.z + v.w * v.w;
      ss = wave_sum(ss);
      if (lane == 0) sred[w] = ss;
      __syncthreads();
      float nrm = fmaxf(sqrtf(sred[0] + sred[1] + sred[2] + sred[3]), 1e-12f);
      dst[t] = v / nrm;
    }
  } else {
    int row = b - 4096;
    f32x4 v = ((const f32x4*)(l_memory + (size_t)row * DIMV))[t];
    if (row == lj) {
      // recompute out_m[mi] inline (avoids cross-block dependency on out_m)
      int mode = 0;
      if ((branch == 0 && mi == i1) || (branch == 2 && mi == i2)) mode = 1;
      else if (branch == 1 && mi == i1) mode = 2;
      else if (branch == 2 && mi == i1) mode = 3;
      f32x4 mv;
      if (mode == 0) {
        mv = ((const f32x4*)(m + (size_t)mi * DIMV))[t];
      } else if (mode == 1) {
        mv = ((const f32x4*)(out_s + (size_t)best * DIMV))[t];
      } else {
        f32x4 a = ((const f32x4*)(m + (size_t)mi * DIMV))[t];
        f32x4 bb = (mode == 2) ? ((const f32x4*)(out_s + (size_t)best * DIMV))[t]
                               : ((const f32x4*)(m + (size_t)i2 * DIMV))[t];
        f32x4 vm = (a + bb) * 0.5f;
        float ss = vm.x * vm.x + vm.y * vm.y + vm.z * vm.z + vm.w * vm.w;
        ss = wave_sum(ss);
        if (lane == 0) sred[w] = ss;
        __syncthreads();
        float nrm = fmaxf(sqrtf(sred[0] + sred[1] + sred[2] + sred[3]), 1e-12f);
        mv = vm / nrm;
      }
      v = v * 0.9f + mv * 0.1f;
    }
    ((f32x4*)(out_l + (size_t)row * DIMV))[t] = v;
  }
}

extern "C" void kernel_launch(void* const* d_in, const int* in_sizes, int n_in,
                              void* d_out, int out_size, void* d_ws, size_t ws_size,
                              hipStream_t stream) {
  const float* cand = (const float*)d_in[0];
  const float* s_memory = (const float*)d_in[1];
  const float* m_memory = (const float*)d_in[2];
  const float* l_memory = (const float*)d_in[3];
  const float* m_utility = (const float*)d_in[4];
  const float* l_utility = (const float*)d_in[5];
  const float* wq = (const float*)d_in[6];
  const float* bq = (const float*)d_in[7];
  const float* wk = (const float*)d_in[8];
  const float* bk = (const float*)d_in[9];
  const int* s_ptr = (const int*)d_in[10];
  (void)bk;  // bk.q is a constant logit shift -> argmax-invariant

  float* out = (float*)d_out;
  float* out_s = out + OUT_S;
  float* out_m = out + OUT_M;
  float* out_l = out + OUT_L;
  float* out_mu = out + OUT_MU;
  float* out_lu = out + OUT_LU;
  float* out_sptr = out + OUT_SPTR;

  float* lsc = out_l;  // scratch region: fully consumed before kI overwrites it
  unsigned short* mb = (unsigned short*)(lsc + SC_BF16);
  float* norms = lsc + SC_NORMS;
  int* topidx = (int*)(lsc + SC_TOPIDX);
  float* lpart = lsc + SC_LPART;
  float* rv = lsc + SC_RV;
  float* lmean = lsc + SC_LMEAN;
  float* qv = lsc + SC_Q;
  float* logits = lsc + SC_LOGITS;
  int* best = (int*)(lsc + SC_BEST);
  float* cnorm = lsc + SC_BEST + 1;
  float* mnorm = lsc + SC_MNORM;
  float* sims = lsc + SC_SIMS;
  float* pv = lsc + SC_PPV;
  int* pidx = (int*)(lsc + SC_PPI);
  int* wsctl = (int*)d_ws;  // 24 B control block, read by kI after scratch is dead

  hipMemsetAsync(rv, 0, 4096, stream);  // rv accumulator zero
  kA<<<5248, 256, 0, stream>>>(cand, l_memory, m_memory, norms, lpart, mb, mnorm);
  kT<<<2, 1024, 0, stream>>>(norms, topidx, lpart, lmean);
  kB<<<768, 256, 0, stream>>>(cand, s_memory, topidx, s_ptr, wq, bq, lmean, out_s, out_sptr, qv);
  kC<<<128, 256, 0, stream>>>(wk, qv, rv);
  kD<<<128, 256, 0, stream>>>(out_s, rv, logits);
  kE<<<1, 256, 0, stream>>>(logits, out_s, best, cnorm);
  kG<<<NPAIR + 1024, 256, 0, stream>>>(mb, mnorm, m_memory, out_s, best, cnorm, pv, pidx, sims);
  kH<<<1, 1024, 0, stream>>>(pv, pidx, sims, m_utility, mnorm, cnorm, best, l_utility,
                             out_mu, out_lu, wsctl);
  kI<<<12288, 256, 0, stream>>>(m_memory, l_memory, out_s, wsctl, out_m, out_l);
}